// Round 2
// baseline (213.879 us; speedup 1.0000x reference)
//
#include <hip/hip_runtime.h>

// Problem constants (from reference): B=16, L=4096, D=512, HORIZON=100
constexpr int Bc = 16;
constexpr int Lc = 4096;
constexpr int Dc = 512;
constexpr int PAIR_PER_ROW = Dc / 8;          // 64 8-float chunks per row
constexpr int ROWS = Bc * (Lc + 1);           // 65552
constexpr int TOTALP = ROWS * PAIR_PER_ROW;   // 4,195,328  (exactly divisible by 256)

// clang native vector type — accepted by __builtin_nontemporal_{load,store}
typedef float v4f __attribute__((ext_vector_type(4)));

__global__ __launch_bounds__(256) void pe_kernel(
    const float* __restrict__ tokens,
    const int*   __restrict__ lengths,
    const float* __restrict__ cls,
    float*       __restrict__ out)
{
    // One thread = one 8-float (32 B) chunk; one wave = one full 512-float row,
    // so the (l<len / l==len / l>len) branch is wave-uniform.
    int t = blockIdx.x * 256 + threadIdx.x;     // pair index; grid is exact, no tail

    int p   = t & (PAIR_PER_ROW - 1);           // which 8-float chunk within the row
    int row = t >> 6;                           // t / 64
    int b   = row / (Lc + 1);
    int l   = row - b * (Lc + 1);
    int len = lengths[b];
    int d0  = p << 3;                           // element index (multiple of 8)

    v4f r0, r1;
    if (l < len) {
        // valid token row (l < len <= L, so l indexes tokens). Streamed once: nt load.
        const v4f* src = reinterpret_cast<const v4f*>(
            tokens + ((size_t)(b * Lc + l) << 9) + d0);
        v4f ta = __builtin_nontemporal_load(src);
        v4f tb = __builtin_nontemporal_load(src + 1);

        // coef(d) = 100^{-(d - d%2)/512} + (pi/2)*(d%2); work in revolutions.
        // freq_rev = exp2(-(d&~1) * log2(100)/512) / (2*pi); phase_rev = 0.25*(d&1)
        const float K      = 6.6438561897747395f / 512.0f;  // log2(100)/512
        const float INV2PI = 0.15915493667125702f;          // 1/(2*pi)

        float f0 = __builtin_exp2f(-(float)(d0    ) * K) * INV2PI;
        float f2 = __builtin_exp2f(-(float)(d0 + 2) * K) * INV2PI;
        float f4 = __builtin_exp2f(-(float)(d0 + 4) * K) * INV2PI;
        float f6 = __builtin_exp2f(-(float)(d0 + 6) * K) * INV2PI;

        float lf = (float)l;
        r0.x = ta.x + __builtin_amdgcn_sinf(__builtin_amdgcn_fractf(lf * f0));
        r0.y = ta.y + __builtin_amdgcn_sinf(__builtin_amdgcn_fractf(lf * (f0 + 0.25f)));
        r0.z = ta.z + __builtin_amdgcn_sinf(__builtin_amdgcn_fractf(lf * f2));
        r0.w = ta.w + __builtin_amdgcn_sinf(__builtin_amdgcn_fractf(lf * (f2 + 0.25f)));
        r1.x = tb.x + __builtin_amdgcn_sinf(__builtin_amdgcn_fractf(lf * f4));
        r1.y = tb.y + __builtin_amdgcn_sinf(__builtin_amdgcn_fractf(lf * (f4 + 0.25f)));
        r1.z = tb.z + __builtin_amdgcn_sinf(__builtin_amdgcn_fractf(lf * f6));
        r1.w = tb.w + __builtin_amdgcn_sinf(__builtin_amdgcn_fractf(lf * (f6 + 0.25f)));
    } else if (l == len) {
        // CLS row gets exactly cls. cls is hot in L2 (reused by 16*64 waves): cached load.
        const v4f* c4 = reinterpret_cast<const v4f*>(cls + d0);
        r0 = c4[0];
        r1 = c4[1];
    } else {
        r0 = (v4f){0.f, 0.f, 0.f, 0.f};
        r1 = r0;
    }

    // Pure streaming output, never re-read: nontemporal store.
    v4f* dst = reinterpret_cast<v4f*>(out) + ((size_t)t << 1);
    __builtin_nontemporal_store(r0, dst);
    __builtin_nontemporal_store(r1, dst + 1);
}

extern "C" void kernel_launch(void* const* d_in, const int* in_sizes, int n_in,
                              void* d_out, int out_size, void* d_ws, size_t ws_size,
                              hipStream_t stream) {
    const float* tokens  = (const float*)d_in[0];
    const int*   lengths = (const int*)d_in[1];
    const float* cls     = (const float*)d_in[2];
    float*       out     = (float*)d_out;

    int blocks = TOTALP / 256;   // 16388, exact
    pe_kernel<<<blocks, 256, 0, stream>>>(tokens, lengths, cls, out);
}

// Round 3
// 210.347 us; speedup vs baseline: 1.0168x; 1.0168x over previous
//
#include <hip/hip_runtime.h>

// Problem constants (from reference): B=16, L=4096, D=512, HORIZON=100
constexpr int Bc = 16;
constexpr int Lc = 4096;
constexpr int Dc = 512;
constexpr int F4_PER_ROW = Dc / 4;            // 128 float4 per row
constexpr int CHUNKS = F4_PER_ROW / 2;        // 64 lanes: lane p owns float4 p and p+64
constexpr int ROWS = Bc * (Lc + 1);           // 65552
constexpr int TOTALP = ROWS * CHUNKS;         // 4,195,328  (exactly divisible by 256)

// clang native vector type — accepted by __builtin_nontemporal_{load,store}
typedef float v4f __attribute__((ext_vector_type(4)));

__global__ __launch_bounds__(256) void pe_kernel(
    const float* __restrict__ tokens,
    const int*   __restrict__ lengths,
    const float* __restrict__ cls,
    float*       __restrict__ out)
{
    // One wave = one full 512-float row. Lane p owns float4 #p and #(p+64),
    // so EVERY load/store instruction is a dense contiguous 1 KB across the wave
    // (previous version interleaved 16B@32B-stride, splitting every 64B line
    // across two instructions).
    int t = blockIdx.x * 256 + threadIdx.x;     // grid is exact, no tail

    int p   = t & (CHUNKS - 1);                 // float4 index of first chunk (0..63)
    int row = t >> 6;                           // t / 64
    int b   = row / (Lc + 1);
    int l   = row - b * (Lc + 1);
    int len = lengths[b];
    int d0  = p << 2;                           // element index of first chunk (0..252)

    v4f r0, r1;
    if (l < len) {
        // valid token row (l < len <= L). Streamed once: nt loads, dense per instr.
        const v4f* src = reinterpret_cast<const v4f*>(tokens)
                       + ((size_t)(b * Lc + l) << 7);
        v4f ta = __builtin_nontemporal_load(src + p);
        v4f tb = __builtin_nontemporal_load(src + p + 64);

        // coef(d) = 100^{-(d - d%2)/512} + (pi/2)*(d%2); work in revolutions.
        // freq_rev(d) = exp2(-(d&~1)*log2(100)/512) / (2*pi); phase_rev = 0.25*(d&1)
        // Second chunk is d+256: freq scales by 100^{-256/512} = 0.1 exactly.
        const float K      = 6.6438561897747395f / 512.0f;  // log2(100)/512
        const float INV2PI = 0.15915493667125702f;          // 1/(2*pi)

        float f0  = __builtin_exp2f(-(float)(d0    ) * K) * INV2PI;  // d0, d0+1
        float f2  = __builtin_exp2f(-(float)(d0 + 2) * K) * INV2PI;  // d0+2, d0+3
        float f0b = f0 * 0.1f;                                       // d0+256
        float f2b = f2 * 0.1f;                                       // d0+258

        float lf = (float)l;
        r0.x = ta.x + __builtin_amdgcn_sinf(__builtin_amdgcn_fractf(lf * f0));
        r0.y = ta.y + __builtin_amdgcn_sinf(__builtin_amdgcn_fractf(lf * (f0 + 0.25f)));
        r0.z = ta.z + __builtin_amdgcn_sinf(__builtin_amdgcn_fractf(lf * f2));
        r0.w = ta.w + __builtin_amdgcn_sinf(__builtin_amdgcn_fractf(lf * (f2 + 0.25f)));
        r1.x = tb.x + __builtin_amdgcn_sinf(__builtin_amdgcn_fractf(lf * f0b));
        r1.y = tb.y + __builtin_amdgcn_sinf(__builtin_amdgcn_fractf(lf * (f0b + 0.25f)));
        r1.z = tb.z + __builtin_amdgcn_sinf(__builtin_amdgcn_fractf(lf * f2b));
        r1.w = tb.w + __builtin_amdgcn_sinf(__builtin_amdgcn_fractf(lf * (f2b + 0.25f)));
    } else if (l == len) {
        // CLS row gets exactly cls. cls is L2-hot (reused by all 16 batches): cached load.
        const v4f* c4 = reinterpret_cast<const v4f*>(cls);
        r0 = c4[p];
        r1 = c4[p + 64];
    } else {
        r0 = (v4f){0.f, 0.f, 0.f, 0.f};
        r1 = r0;
    }

    // Pure streaming output, never re-read: nt stores, dense 1 KB per instruction.
    v4f* dst = reinterpret_cast<v4f*>(out) + ((size_t)row << 7);
    __builtin_nontemporal_store(r0, dst + p);
    __builtin_nontemporal_store(r1, dst + p + 64);
}

extern "C" void kernel_launch(void* const* d_in, const int* in_sizes, int n_in,
                              void* d_out, int out_size, void* d_ws, size_t ws_size,
                              hipStream_t stream) {
    const float* tokens  = (const float*)d_in[0];
    const int*   lengths = (const int*)d_in[1];
    const float* cls     = (const float*)d_in[2];
    float*       out     = (float*)d_out;

    int blocks = TOTALP / 256;   // 16388, exact
    pe_kernel<<<blocks, 256, 0, stream>>>(tokens, lengths, cls, out);
}